// Round 7
// baseline (433.944 us; speedup 1.0000x reference)
//
#include <hip/hip_runtime.h>
#include <hip/hip_bf16.h>

// GCN: 4 layers, D^{-1/2}(A+I)D^{-1/2} aggregation, log_softmax output.
// CSR per call (bucketed build, R6); u = dinv*(h@W) pre-scale, CSR gather,
// post-scale dinv[dst], self-loop folded. Layer1/4 transform BEFORE agg.
// R6: bucket CSR build (654->407us).
// R7: t768 was LDS-instr-bound (1 W-read/k/lane) -> wave owns 64 nodes,
//     4 nodes/lane, DPP quad-broadcast x, W-read amortized 4x, XOR-swizzled
//     x tile. Fused t16 into agg epilogue (agg and transform commute):
//     gather v=dinv*h, epilogue 16x16 matmul via xor-distributed quad lanes.

#define DIVUP(a, b) (((a) + (b) - 1) / (b))
#define NBUCK 128
#define BSHIFT 10
#define BCAP 36864

// ---------- edge dtype detection ----------
__global__ void k_detect(const void* ei, int* flag) {
    int t = threadIdx.x;
    const int* p = (const int*)ei;
    bool z = (p[2 * t + 1] == 0);
    unsigned long long m = __ballot(z);
    if (t == 0) *flag = (m == ~0ULL) ? 1 : 0;
}

__device__ __forceinline__ int load_idx(const void* ei, int is64, size_t pos) {
    if (is64) return (int)((const long long*)ei)[pos];
    return ((const int*)ei)[pos];
}

__global__ void k_zero(int* gcur) { gcur[threadIdx.x] = 0; }

// ---------- pass 1: bucket edges by dst>>10 ----------
__global__ void k_bucket(const void* ei, const int* flag, int* gcur,
                         int2* ebuf, int E) {
    __shared__ int hist[NBUCK];
    __shared__ int base[NBUCK];
    int tid = threadIdx.x;
    if (tid < NBUCK) hist[tid] = 0;
    __syncthreads();
    int is64 = *flag;
    int ebase = blockIdx.x * 2048 + tid;
    int s[8], d[8], r[8], bk[8];
    bool ok[8];
#pragma unroll
    for (int j = 0; j < 8; ++j) {
        int e = ebase + j * 256;
        ok[j] = (e < E);
        s[j] = ok[j] ? load_idx(ei, is64, (size_t)e) : 0;
        d[j] = ok[j] ? load_idx(ei, is64, (size_t)E + e) : 0;
        bk[j] = d[j] >> BSHIFT;
    }
#pragma unroll
    for (int j = 0; j < 8; ++j)
        r[j] = ok[j] ? atomicAdd(&hist[bk[j]], 1) : 0;
    __syncthreads();
    if (tid < NBUCK && hist[tid] > 0)
        base[tid] = atomicAdd(&gcur[tid], hist[tid]);
    __syncthreads();
#pragma unroll
    for (int j = 0; j < 8; ++j)
        if (ok[j])
            ebuf[(size_t)bk[j] * BCAP + base[bk[j]] + r[j]] = make_int2(s[j], d[j]);
}

// ---------- pass 2a: per-bucket degree histogram ----------
__global__ void k_hist(const int2* __restrict__ ebuf, const int* __restrict__ gcur,
                       int* __restrict__ cnt, int n) {
    __shared__ int deg[1024];
    int b = blockIdx.x, tid = threadIdx.x;
    for (int j = tid; j < 1024; j += 512) deg[j] = 0;
    __syncthreads();
    int S = gcur[b], lo = b << BSHIFT;
    const int2* eb = ebuf + (size_t)b * BCAP;
    for (int i = tid; i < S; i += 2048) {
        int2 e0, e1, e2, e3;
        bool o1 = i + 512 < S, o2 = i + 1024 < S, o3 = i + 1536 < S;
        e0 = eb[i];
        e1 = o1 ? eb[i + 512] : e0;
        e2 = o2 ? eb[i + 1024] : e0;
        e3 = o3 ? eb[i + 1536] : e0;
        atomicAdd(&deg[e0.y - lo], 1);
        if (o1) atomicAdd(&deg[e1.y - lo], 1);
        if (o2) atomicAdd(&deg[e2.y - lo], 1);
        if (o3) atomicAdd(&deg[e3.y - lo], 1);
    }
    __syncthreads();
    for (int j = tid; j < 1024; j += 512)
        if (lo + j < n) cnt[lo + j] = deg[j];
}

// ---------- exclusive scan ----------
__global__ void k_scanA(const int* cnt, int* offs, int* bsums, int n) {
    __shared__ int s[256];
    int t = threadIdx.x;
    int i = blockIdx.x * 256 + t;
    int v = (i < n) ? cnt[i] : 0;
    s[t] = v;
    __syncthreads();
    for (int off = 1; off < 256; off <<= 1) {
        int add = (t >= off) ? s[t - off] : 0;
        __syncthreads();
        s[t] += add;
        __syncthreads();
    }
    if (i < n) offs[i] = s[t] - v;
    if (t == 255) bsums[blockIdx.x] = s[t];
}

__global__ void k_scanB(int* bsums, int nb) {
    __shared__ int s[512];
    int t = threadIdx.x;
    int v = (t < nb) ? bsums[t] : 0;
    s[t] = v;
    __syncthreads();
    for (int off = 1; off < 512; off <<= 1) {
        int add = (t >= off) ? s[t - off] : 0;
        __syncthreads();
        s[t] += add;
        __syncthreads();
    }
    if (t < nb) bsums[t] = s[t] - v;
}

__global__ void k_scanC(int* offs, const int* bsums, const int* cnt, float* dinv, int n) {
    int i = blockIdx.x * 256 + threadIdx.x;
    if (i >= n) return;
    offs[i] += bsums[blockIdx.x];
    dinv[i] = rsqrtf((float)(cnt[i] + 1));
}

// ---------- pass 2b: CSR fill ----------
__global__ void k_fillb(const int2* __restrict__ ebuf, const int* __restrict__ gcur,
                        const int* __restrict__ offs, int* __restrict__ col, int n) {
    __shared__ int cur[1024];
    int b = blockIdx.x, tid = threadIdx.x;
    int lo = b << BSHIFT;
    for (int j = tid; j < 1024; j += 512)
        cur[j] = (lo + j < n) ? offs[lo + j] : 0;
    __syncthreads();
    int S = gcur[b];
    const int2* eb = ebuf + (size_t)b * BCAP;
    for (int i = tid; i < S; i += 2048) {
        int2 e0, e1, e2, e3;
        bool o1 = i + 512 < S, o2 = i + 1024 < S, o3 = i + 1536 < S;
        e0 = eb[i];
        e1 = o1 ? eb[i + 512] : e0;
        e2 = o2 ? eb[i + 1024] : e0;
        e3 = o3 ? eb[i + 1536] : e0;
        int p0 = atomicAdd(&cur[e0.y - lo], 1);
        int p1 = o1 ? atomicAdd(&cur[e1.y - lo], 1) : 0;
        int p2 = o2 ? atomicAdd(&cur[e2.y - lo], 1) : 0;
        int p3 = o3 ? atomicAdd(&cur[e3.y - lo], 1) : 0;
        col[p0] = e0.x;
        if (o1) col[p1] = e1.x;
        if (o2) col[p2] = e2.x;
        if (o3) col[p3] = e3.x;
    }
}

__device__ __forceinline__ void fma4(float s, const float4 w, float4& a) {
    a.x = fmaf(s, w.x, a.x);
    a.y = fmaf(s, w.y, a.y);
    a.z = fmaf(s, w.z, a.z);
    a.w = fmaf(s, w.w, a.w);
}

// DPP quad_perm broadcast of lane J within each 4-lane quad (VALU, no LDS)
template <int J>
__device__ __forceinline__ float qb1(float v) {
    constexpr int ctrl = J | (J << 2) | (J << 4) | (J << 6);
    return __int_as_float(
        __builtin_amdgcn_mov_dpp(__float_as_int(v), ctrl, 0xF, 0xF, true));
}
template <int J>
__device__ __forceinline__ float4 qb4(float4 v) {
    float4 r;
    r.x = qb1<J>(v.x); r.y = qb1<J>(v.y); r.z = qb1<J>(v.z); r.w = qb1<J>(v.w);
    return r;
}

// ---------- layer-1 transform, k-split: parts[slice] = x[:,slice] @ W1[slice] ----------
// Block 256 = 4 waves, all on the SAME 192-k slice; each wave owns 64 nodes,
// each lane owns 4 nodes (its quad) x 4 out-dims (og). x tile [64][32k] per
// wave, XOR-swizzled (conflict-free b128); DPP quad-broadcast shares x within
// the quad; W read once per k per lane, amortized over 4 nodes.
__global__ void k_transform768(const float* __restrict__ x, const float* __restrict__ W,
                               float* __restrict__ parts, int n) {
    __shared__ float Wl[192 * 20];     // 15360 B
    __shared__ float lx[4][64 * 32];   // 32768 B (per-wave 64 nodes x 32 k)
    int slice = blockIdx.x & 3;
    int nblk = blockIdx.x >> 2;
    int tid = threadIdx.x, wid = tid >> 6, lane = tid & 63;
    int og = lane & 3;
    int nq4 = lane & ~3;               // quad's base node (0..60)
    int nbw = nblk * 256 + wid * 64;   // wave's node base
    const float4* xg = (const float4*)x;
    const float4* wg = (const float4*)W;

    for (int i = tid; i < 768; i += 256) {
        float4 v = wg[slice * 768 + i];
        *(float4*)&Wl[(i >> 2) * 20 + (i & 3) * 4] = v;
    }
    __syncthreads();

    float* lw = lx[wid];
    float4 acc0 = {0, 0, 0, 0}, acc1 = acc0, acc2 = acc0, acc3 = acc0;
    const float4 z4 = {0, 0, 0, 0};
#pragma unroll 1
    for (int t = 0; t < 6; ++t) {
        // stage 64 nodes x 8 float4 (32 k), col-swizzled
        float4 rg[8];
#pragma unroll
        for (int r = 0; r < 8; ++r) {
            int f = r * 64 + lane;
            int nd = f >> 3, c = f & 7;
            int gn = nbw + nd;
            rg[r] = (gn < n) ? xg[(size_t)gn * 192 + slice * 48 + t * 8 + c] : z4;
        }
#pragma unroll
        for (int r = 0; r < 8; ++r) {
            int f = r * 64 + lane;
            int nd = f >> 3, c = f & 7;
            *(float4*)&lw[nd * 32 + ((c ^ (nd & 7)) << 2)] = rg[r];
        }
        // compute 32 k (wave-private LDS; per-wave DS ordering keeps RAW safe)
#pragma unroll
        for (int c = 0; c < 8; ++c) {
            float4 xm = *(const float4*)&lw[lane * 32 + ((c ^ (lane & 7)) << 2)];
            float4 x0 = qb4<0>(xm), x1 = qb4<1>(xm), x2 = qb4<2>(xm), x3 = qb4<3>(xm);
#pragma unroll
            for (int kk = 0; kk < 4; ++kk) {
                const float4 w = *(const float4*)&Wl[(t * 32 + c * 4 + kk) * 20 + og * 4];
                fma4((&x0.x)[kk], w, acc0);
                fma4((&x1.x)[kk], w, acc1);
                fma4((&x2.x)[kk], w, acc2);
                fma4((&x3.x)[kk], w, acc3);
            }
        }
    }
    float4* dst = (float4*)(parts + (size_t)slice * n * 16);
    if (nbw + nq4 + 0 < n) dst[(size_t)(nbw + nq4 + 0) * 4 + og] = acc0;
    if (nbw + nq4 + 1 < n) dst[(size_t)(nbw + nq4 + 1) * 4 + og] = acc1;
    if (nbw + nq4 + 2 < n) dst[(size_t)(nbw + nq4 + 2) * 4 + og] = acc2;
    if (nbw + nq4 + 3 < n) dst[(size_t)(nbw + nq4 + 3) * 4 + og] = acc3;
}

// ---------- reduce 4 partials, apply dinv: u = dinv * sum parts ----------
__global__ void k_red4(const float* __restrict__ parts, const float* __restrict__ dinv,
                       float* __restrict__ u, int n) {
    int g = blockIdx.x * 256 + threadIdx.x;
    if (g >= 4 * n) return;
    size_t stride = (size_t)n * 4;
    const float4* p = (const float4*)parts;
    float4 a = p[g], b = p[g + stride], c = p[g + 2 * stride], d = p[g + 3 * stride];
    float s = dinv[g >> 2];
    float4 r;
    r.x = (a.x + b.x + c.x + d.x) * s;
    r.y = (a.y + b.y + c.y + d.y) * s;
    r.z = (a.z + b.z + c.z + d.z) * s;
    r.w = (a.w + b.w + c.w + d.w) * s;
    ((float4*)u)[g] = r;
}

// ---------- layer-1 aggregate: v1 = dinv * relu(dinv*(sum u + self) + b) ----------
__global__ void k_agg16A(const float* __restrict__ u, const int* __restrict__ col,
                         const int* __restrict__ offs, const int* __restrict__ cnt,
                         const float* __restrict__ dinv, const float* __restrict__ b,
                         float* __restrict__ vout, int n) {
    int wave = threadIdx.x >> 6;
    int node = blockIdx.x * 4 + wave;
    if (node >= n) return;
    int lane = threadIdx.x & 63;
    int eslot = lane >> 2, comp = lane & 3;
    const float4* u4 = (const float4*)u;
    int beg = offs[node], c = cnt[node];
    float4 a0 = {0, 0, 0, 0}, a1 = a0, a2 = a0, a3 = a0;
    int i = eslot;
    for (; i + 48 < c; i += 64) {
        int s0 = col[beg + i], s1 = col[beg + i + 16];
        int s2 = col[beg + i + 32], s3 = col[beg + i + 48];
        float4 v0 = u4[(size_t)s0 * 4 + comp];
        float4 v1 = u4[(size_t)s1 * 4 + comp];
        float4 v2 = u4[(size_t)s2 * 4 + comp];
        float4 v3 = u4[(size_t)s3 * 4 + comp];
        a0.x += v0.x; a0.y += v0.y; a0.z += v0.z; a0.w += v0.w;
        a1.x += v1.x; a1.y += v1.y; a1.z += v1.z; a1.w += v1.w;
        a2.x += v2.x; a2.y += v2.y; a2.z += v2.z; a2.w += v2.w;
        a3.x += v3.x; a3.y += v3.y; a3.z += v3.z; a3.w += v3.w;
    }
    for (; i < c; i += 16) {
        int s0 = col[beg + i];
        float4 v0 = u4[(size_t)s0 * 4 + comp];
        a0.x += v0.x; a0.y += v0.y; a0.z += v0.z; a0.w += v0.w;
    }
    a0.x += a1.x + a2.x + a3.x;
    a0.y += a1.y + a2.y + a3.y;
    a0.z += a1.z + a2.z + a3.z;
    a0.w += a1.w + a2.w + a3.w;
    for (int off = 4; off < 64; off <<= 1) {
        a0.x += __shfl_xor(a0.x, off, 64);
        a0.y += __shfl_xor(a0.y, off, 64);
        a0.z += __shfl_xor(a0.z, off, 64);
        a0.w += __shfl_xor(a0.w, off, 64);
    }
    if (eslot == 0) {
        float4 self = u4[(size_t)node * 4 + comp];
        float dv = dinv[node];
        float4 bb = ((const float4*)b)[comp];
        float4 r;
        r.x = dv * fmaxf(fmaf(dv, a0.x + self.x, bb.x), 0.f);
        r.y = dv * fmaxf(fmaf(dv, a0.y + self.y, bb.y), 0.f);
        r.z = dv * fmaxf(fmaf(dv, a0.z + self.z, bb.z), 0.f);
        r.w = dv * fmaxf(fmaf(dv, a0.w + self.w, bb.w), 0.f);
        ((float4*)vout)[(size_t)node * 4 + comp] = r;
    }
}

// ---------- fused aggregate+transform (layers 2,3) ----------
// gather g = sum v[src] + v[node]; s = dinv*g; h = relu(s@W + b);
// vout = dinv*h. 16x16 matmul distributed over the 4 comp-lanes via xor trick.
__global__ void k_agg16F(const float* __restrict__ vin, const int* __restrict__ col,
                         const int* __restrict__ offs, const int* __restrict__ cnt,
                         const float* __restrict__ dinv, const float* __restrict__ W,
                         const float* __restrict__ b, float* __restrict__ vout, int n) {
    __shared__ float Wl[16 * 20];
    int tid = threadIdx.x;
    if (tid < 64) {
        float4 w = ((const float4*)W)[tid];
        *(float4*)&Wl[(tid >> 2) * 20 + (tid & 3) * 4] = w;
    }
    __syncthreads();
    int wave = tid >> 6;
    int node = blockIdx.x * 4 + wave;
    if (node >= n) return;
    int lane = tid & 63;
    int eslot = lane >> 2, comp = lane & 3;
    const float4* v4 = (const float4*)vin;
    int beg = offs[node], c = cnt[node];
    float4 self = v4[(size_t)node * 4 + comp];
    float dv = dinv[node];
    float4 a0 = {0, 0, 0, 0}, a1 = a0, a2 = a0, a3 = a0;
    int i = eslot;
    for (; i + 48 < c; i += 64) {
        int s0 = col[beg + i], s1 = col[beg + i + 16];
        int s2 = col[beg + i + 32], s3 = col[beg + i + 48];
        float4 v0 = v4[(size_t)s0 * 4 + comp];
        float4 v1 = v4[(size_t)s1 * 4 + comp];
        float4 v2 = v4[(size_t)s2 * 4 + comp];
        float4 v3 = v4[(size_t)s3 * 4 + comp];
        a0.x += v0.x; a0.y += v0.y; a0.z += v0.z; a0.w += v0.w;
        a1.x += v1.x; a1.y += v1.y; a1.z += v1.z; a1.w += v1.w;
        a2.x += v2.x; a2.y += v2.y; a2.z += v2.z; a2.w += v2.w;
        a3.x += v3.x; a3.y += v3.y; a3.z += v3.z; a3.w += v3.w;
    }
    for (; i < c; i += 16) {
        int s0 = col[beg + i];
        float4 v0 = v4[(size_t)s0 * 4 + comp];
        a0.x += v0.x; a0.y += v0.y; a0.z += v0.z; a0.w += v0.w;
    }
    a0.x += a1.x + a2.x + a3.x;
    a0.y += a1.y + a2.y + a3.y;
    a0.z += a1.z + a2.z + a3.z;
    a0.w += a1.w + a2.w + a3.w;
    for (int off = 4; off < 64; off <<= 1) {
        a0.x += __shfl_xor(a0.x, off, 64);
        a0.y += __shfl_xor(a0.y, off, 64);
        a0.z += __shfl_xor(a0.z, off, 64);
        a0.w += __shfl_xor(a0.w, off, 64);
    }
    // s = dv*(gather + self) : lane holds k-slice [comp*4, comp*4+4)
    float4 s;
    s.x = dv * (a0.x + self.x);
    s.y = dv * (a0.y + self.y);
    s.z = dv * (a0.z + self.z);
    s.w = dv * (a0.w + self.w);
    // p[m] = partial for output-group (comp^m) over this lane's k-slice
    float4 p0 = {0, 0, 0, 0}, p1 = p0, p2 = p0, p3 = p0;
    const float* wr = &Wl[comp * 4 * 20];
#pragma unroll
    for (int i2 = 0; i2 < 4; ++i2) {
        float si = (&s.x)[i2];
        const float* row = wr + i2 * 20;
        fma4(si, *(const float4*)&row[((comp ^ 0) << 2)], p0);
        fma4(si, *(const float4*)&row[((comp ^ 1) << 2)], p1);
        fma4(si, *(const float4*)&row[((comp ^ 2) << 2)], p2);
        fma4(si, *(const float4*)&row[((comp ^ 3) << 2)], p3);
    }
    float4 o;
    o.x = p0.x + __shfl_xor(p1.x, 1, 64) + __shfl_xor(p2.x, 2, 64) + __shfl_xor(p3.x, 3, 64);
    o.y = p0.y + __shfl_xor(p1.y, 1, 64) + __shfl_xor(p2.y, 2, 64) + __shfl_xor(p3.y, 3, 64);
    o.z = p0.z + __shfl_xor(p1.z, 1, 64) + __shfl_xor(p2.z, 2, 64) + __shfl_xor(p3.z, 3, 64);
    o.w = p0.w + __shfl_xor(p1.w, 1, 64) + __shfl_xor(p2.w, 2, 64) + __shfl_xor(p3.w, 3, 64);
    if (eslot == 0) {
        float4 bb = ((const float4*)b)[comp];
        float4 r;
        r.x = dv * fmaxf(o.x + bb.x, 0.f);
        r.y = dv * fmaxf(o.y + bb.y, 0.f);
        r.z = dv * fmaxf(o.z + bb.z, 0.f);
        r.w = dv * fmaxf(o.w + bb.w, 0.f);
        ((float4*)vout)[(size_t)node * 4 + comp] = r;
    }
}

// ---------- layer-4 transform: u4 = v3 @ W4 (dinv already folded into v3) ----------
__global__ void k_t4(const float* __restrict__ v3, const float* __restrict__ W4,
                     float4* __restrict__ u4p, int n) {
    int node = blockIdx.x * 256 + threadIdx.x;
    if (node >= n) return;
    const float4* hr = (const float4*)(v3 + (size_t)node * 16);
    float4 h0 = hr[0], h1 = hr[1], h2 = hr[2], h3 = hr[3];
    float hv[16] = {h0.x, h0.y, h0.z, h0.w, h1.x, h1.y, h1.z, h1.w,
                    h2.x, h2.y, h2.z, h2.w, h3.x, h3.y, h3.z, h3.w};
    float a0 = 0.f, a1 = 0.f, a2 = 0.f;
#pragma unroll
    for (int k = 0; k < 16; ++k) {
        a0 = fmaf(hv[k], W4[k * 3 + 0], a0);
        a1 = fmaf(hv[k], W4[k * 3 + 1], a1);
        a2 = fmaf(hv[k], W4[k * 3 + 2], a2);
    }
    u4p[node] = make_float4(a0, a1, a2, 0.f);
}

// ---------- final aggregate + log_softmax ----------
__global__ void k_agg_out(const float4* __restrict__ u4p, const int* __restrict__ col,
                          const int* __restrict__ offs, const int* __restrict__ cnt,
                          const float* __restrict__ dinv, const float* __restrict__ b4,
                          float* __restrict__ out, int n) {
    int wave = threadIdx.x >> 6;
    int node = blockIdx.x * 4 + wave;
    if (node >= n) return;
    int lane = threadIdx.x & 63;
    int beg = offs[node], c = cnt[node];
    float a0 = 0.f, a1 = 0.f, a2 = 0.f;
    for (int i = lane; i < c; i += 64) {
        float4 v = u4p[col[beg + i]];
        a0 += v.x; a1 += v.y; a2 += v.z;
    }
    for (int off = 1; off < 64; off <<= 1) {
        a0 += __shfl_xor(a0, off, 64);
        a1 += __shfl_xor(a1, off, 64);
        a2 += __shfl_xor(a2, off, 64);
    }
    if (lane == 0) {
        float4 self = u4p[node];
        float dv = dinv[node];
        float v0 = fmaf(dv, a0 + self.x, b4[0]);
        float v1 = fmaf(dv, a1 + self.y, b4[1]);
        float v2 = fmaf(dv, a2 + self.z, b4[2]);
        float m = fmaxf(v0, fmaxf(v1, v2));
        float lse = m + logf(expf(v0 - m) + expf(v1 - m) + expf(v2 - m));
        out[(size_t)node * 3 + 0] = v0 - lse;
        out[(size_t)node * 3 + 1] = v1 - lse;
        out[(size_t)node * 3 + 2] = v2 - lse;
    }
}

extern "C" void kernel_launch(void* const* d_in, const int* in_sizes, int n_in,
                              void* d_out, int out_size, void* d_ws, size_t ws_size,
                              hipStream_t stream) {
    const float* x  = (const float*)d_in[0];
    const void*  ei = d_in[1];
    const float* W1 = (const float*)d_in[2];
    const float* b1 = (const float*)d_in[3];
    const float* W2 = (const float*)d_in[4];
    const float* b2 = (const float*)d_in[5];
    const float* W3 = (const float*)d_in[6];
    const float* b3 = (const float*)d_in[7];
    const float* W4 = (const float*)d_in[8];
    const float* b4 = (const float*)d_in[9];
    float* out = (float*)d_out;

    const int N = in_sizes[0] / 768;
    const int E = in_sizes[1] / 2;

    char* p = (char*)d_ws;
    auto alloc = [&](size_t bytes) {
        void* r = (void*)p;
        p += (bytes + 255) & ~(size_t)255;
        return r;
    };
    int*   cnt   = (int*)alloc((size_t)N * 4);
    int*   offs  = (int*)alloc((size_t)N * 4);
    int*   bsums = (int*)alloc(4096);
    int*   flag  = (int*)alloc(256);
    int*   gcur  = (int*)alloc(1024);
    float* dinv  = (float*)alloc((size_t)N * 4);
    int*   col   = (int*)alloc((size_t)E * 4);
    float* bufU  = (float*)alloc((size_t)N * 16 * 4);
    float* bufA  = (float*)alloc((size_t)N * 16 * 4);
    float4* u4p  = (float4*)alloc((size_t)N * 16);
    void* big    = alloc((size_t)NBUCK * BCAP * 8);  // ebuf/parts union
    int2*  ebuf  = (int2*)big;
    float* parts = (float*)big;

    const int nbN = DIVUP(N, 256);
    const int nbB = DIVUP(E, 2048);
    const int nbT = DIVUP(4 * N, 256);
    const int nbA = DIVUP(N, 4);
    const int nbX = DIVUP(N, 256) * 4;   // (nodeblock of 256, slice)

    // CSR build
    k_detect<<<1, 64, 0, stream>>>(ei, flag);
    k_zero<<<1, 128, 0, stream>>>(gcur);
    k_bucket<<<nbB, 256, 0, stream>>>(ei, flag, gcur, ebuf, E);
    k_hist<<<NBUCK, 512, 0, stream>>>(ebuf, gcur, cnt, N);
    k_scanA<<<nbN, 256, 0, stream>>>(cnt, offs, bsums, N);
    k_scanB<<<1, 512, 0, stream>>>(bsums, nbN);
    k_scanC<<<nbN, 256, 0, stream>>>(offs, bsums, cnt, dinv, N);
    k_fillb<<<NBUCK, 512, 0, stream>>>(ebuf, gcur, offs, col, N);

    // layer 1 (t768 after fillb: parts aliases ebuf)
    k_transform768<<<nbX, 256, 0, stream>>>(x, W1, parts, N);
    k_red4<<<nbT, 256, 0, stream>>>(parts, dinv, bufU, N);
    k_agg16A<<<nbA, 256, 0, stream>>>(bufU, col, offs, cnt, dinv, b1, bufA, N);
    // layers 2,3 fused aggregate+transform
    k_agg16F<<<nbA, 256, 0, stream>>>(bufA, col, offs, cnt, dinv, W2, b2, bufU, N);
    k_agg16F<<<nbA, 256, 0, stream>>>(bufU, col, offs, cnt, dinv, W3, b3, bufA, N);
    // layer 4
    k_t4<<<nbN, 256, 0, stream>>>(bufA, W4, u4p, N);
    k_agg_out<<<nbA, 256, 0, stream>>>(u4p, col, offs, cnt, dinv, b4, out, N);
}

// Round 8
// 379.229 us; speedup vs baseline: 1.1443x; 1.1443x over previous
//
#include <hip/hip_runtime.h>
#include <hip/hip_bf16.h>

// GCN: 4 layers, D^{-1/2}(A+I)D^{-1/2} aggregation, log_softmax output.
// CSR per call (bucketed build); u = dinv*(h@W) pre-scale, CSR gather,
// post-scale dinv[dst], self-loop folded. Layer1/4 transform BEFORE agg.
// R6: bucket CSR build (654->407us).
// R7: t768 64-node/wave + DPP REGRESSED (407->434, LDS 48KB -> 3 blk/CU);
//     agg16F fusion ~neutral (kept).
// R8: t768 reverted to R6 form. Gathers: 3 hoisted masked col loads ->
//     all col+gather loads concurrent (pad-row for dead slots), serial tail
//     only for c>48. agg_out same (c<=64 one shot). CSR build tail merged:
//     k_bscan(128) + k_build(count+LDS scan+fill) replaces hist+3scans+fill.

#define DIVUP(a, b) (((a) + (b) - 1) / (b))
#define NBUCK 128
#define BSHIFT 10
#define BCAP 36864

// ---------- edge dtype detection (int64 vs int32 ABI ambiguity) ----------
__global__ void k_detect(const void* ei, int* flag) {
    int t = threadIdx.x;
    const int* p = (const int*)ei;
    bool z = (p[2 * t + 1] == 0);
    unsigned long long m = __ballot(z);
    if (t == 0) *flag = (m == ~0ULL) ? 1 : 0;
}

__device__ __forceinline__ int load_idx(const void* ei, int is64, size_t pos) {
    if (is64) return (int)((const long long*)ei)[pos];
    return ((const int*)ei)[pos];
}

// ---------- zero gcur + pad rows (u/bufA/u4p index n) ----------
__global__ void k_zero(int* gcur, float* bufU, float* bufA, float4* u4p, int n) {
    int t = threadIdx.x;  // 256
    if (t < 128) gcur[t] = 0;
    else if (t < 144) bufU[(size_t)n * 16 + (t - 128)] = 0.f;
    else if (t < 160) bufA[(size_t)n * 16 + (t - 144)] = 0.f;
    else if (t == 160) u4p[n] = make_float4(0.f, 0.f, 0.f, 0.f);
}

// ---------- pass 1: bucket edges by dst>>10 ----------
__global__ void k_bucket(const void* ei, const int* flag, int* gcur,
                         int2* ebuf, int E) {
    __shared__ int hist[NBUCK];
    __shared__ int base[NBUCK];
    int tid = threadIdx.x;
    if (tid < NBUCK) hist[tid] = 0;
    __syncthreads();
    int is64 = *flag;
    int ebase = blockIdx.x * 2048 + tid;
    int s[8], d[8], r[8], bk[8];
    bool ok[8];
#pragma unroll
    for (int j = 0; j < 8; ++j) {
        int e = ebase + j * 256;
        ok[j] = (e < E);
        s[j] = ok[j] ? load_idx(ei, is64, (size_t)e) : 0;
        d[j] = ok[j] ? load_idx(ei, is64, (size_t)E + e) : 0;
        bk[j] = d[j] >> BSHIFT;
    }
#pragma unroll
    for (int j = 0; j < 8; ++j)
        r[j] = ok[j] ? atomicAdd(&hist[bk[j]], 1) : 0;
    __syncthreads();
    if (tid < NBUCK && hist[tid] > 0)
        base[tid] = atomicAdd(&gcur[tid], hist[tid]);
    __syncthreads();
#pragma unroll
    for (int j = 0; j < 8; ++j)
        if (ok[j])
            ebuf[(size_t)bk[j] * BCAP + base[bk[j]] + r[j]] = make_int2(s[j], d[j]);
}

// ---------- scan bucket totals -> bucket bases ----------
__global__ void k_bscan(const int* gcur, int* bbase) {
    __shared__ int s[NBUCK];
    int t = threadIdx.x;  // 128
    int v = gcur[t];
    s[t] = v;
    __syncthreads();
    for (int off = 1; off < NBUCK; off <<= 1) {
        int add = (t >= off) ? s[t - off] : 0;
        __syncthreads();
        s[t] += add;
        __syncthreads();
    }
    bbase[t] = s[t] - v;
}

// ---------- per-bucket: degree count, local scan, offs/cnt/dinv, CSR fill ----------
__global__ void k_build(const int2* __restrict__ ebuf, const int* __restrict__ gcur,
                        const int* __restrict__ bbase, int* __restrict__ offs,
                        int* __restrict__ cnt, float* __restrict__ dinv,
                        int* __restrict__ col, int n) {
    __shared__ int deg[1024];
    __shared__ int ps[512];
    int b = blockIdx.x, tid = threadIdx.x;  // 512 threads
    int lo = b << BSHIFT;
    deg[tid] = 0;
    deg[tid + 512] = 0;
    __syncthreads();
    int S = gcur[b];
    const int2* eb = ebuf + (size_t)b * BCAP;
    // pass 1: count
    for (int i = tid; i < S; i += 2048) {
        int2 e0, e1, e2, e3;
        bool o1 = i + 512 < S, o2 = i + 1024 < S, o3 = i + 1536 < S;
        e0 = eb[i];
        e1 = o1 ? eb[i + 512] : e0;
        e2 = o2 ? eb[i + 1024] : e0;
        e3 = o3 ? eb[i + 1536] : e0;
        atomicAdd(&deg[e0.y - lo], 1);
        if (o1) atomicAdd(&deg[e1.y - lo], 1);
        if (o2) atomicAdd(&deg[e2.y - lo], 1);
        if (o3) atomicAdd(&deg[e3.y - lo], 1);
    }
    __syncthreads();
    // local exclusive scan over 1024 degrees (pairs + Hillis-Steele on 512)
    int d0 = deg[2 * tid], d1 = deg[2 * tid + 1];
    int pair = d0 + d1;
    ps[tid] = pair;
    __syncthreads();
    for (int off = 1; off < 512; off <<= 1) {
        int add = (tid >= off) ? ps[tid - off] : 0;
        __syncthreads();
        ps[tid] += add;
        __syncthreads();
    }
    int o0 = bbase[b] + ps[tid] - pair;
    int o1 = o0 + d0;
    deg[2 * tid] = o0;       // becomes cursor
    deg[2 * tid + 1] = o1;
    int g0 = lo + 2 * tid, g1 = g0 + 1;
    if (g0 < n) { offs[g0] = o0; cnt[g0] = d0; dinv[g0] = rsqrtf((float)(d0 + 1)); }
    if (g1 < n) { offs[g1] = o1; cnt[g1] = d1; dinv[g1] = rsqrtf((float)(d1 + 1)); }
    __syncthreads();
    // pass 2: place
    for (int i = tid; i < S; i += 2048) {
        int2 e0, e1, e2, e3;
        bool o1b = i + 512 < S, o2b = i + 1024 < S, o3b = i + 1536 < S;
        e0 = eb[i];
        e1 = o1b ? eb[i + 512] : e0;
        e2 = o2b ? eb[i + 1024] : e0;
        e3 = o3b ? eb[i + 1536] : e0;
        int p0 = atomicAdd(&deg[e0.y - lo], 1);
        int p1 = o1b ? atomicAdd(&deg[e1.y - lo], 1) : 0;
        int p2 = o2b ? atomicAdd(&deg[e2.y - lo], 1) : 0;
        int p3 = o3b ? atomicAdd(&deg[e3.y - lo], 1) : 0;
        col[p0] = e0.x;
        if (o1b) col[p1] = e1.x;
        if (o2b) col[p2] = e2.x;
        if (o3b) col[p3] = e3.x;
    }
}

__device__ __forceinline__ void fma4(float s, const float4 w, float4& a) {
    a.x = fmaf(s, w.x, a.x);
    a.y = fmaf(s, w.y, a.y);
    a.z = fmaf(s, w.z, a.z);
    a.w = fmaf(s, w.w, a.w);
}

// ---------- layer-1 transform, k-split (R6 form) ----------
__global__ void k_transform768(const float* __restrict__ x, const float* __restrict__ W,
                               float* __restrict__ parts, int n) {
    __shared__ float Wl[192 * 20];
    __shared__ float lx[4][16][68];
    int slice = blockIdx.x & 3;
    int nblk = blockIdx.x >> 2;
    int tid = threadIdx.x;
    int wid = tid >> 6, lane = tid & 63;
    int nbase = nblk * 64 + wid * 16;
    int nloc = lane >> 2, og = lane & 3;
    int node = nbase + nloc;
    const float4* xg = (const float4*)x;
    const float4* wg = (const float4*)W;

#pragma unroll
    for (int i = tid; i < 768; i += 256) {
        float4 v = wg[slice * 768 + i];
        *(float4*)&Wl[(i >> 2) * 20 + (i & 3) * 4] = v;
    }
    __syncthreads();

    float4 acc = {0.f, 0.f, 0.f, 0.f};
    const float* lxr = lx[wid][nloc];
#pragma unroll 1
    for (int t = 0; t < 3; ++t) {
#pragma unroll
        for (int r = 0; r < 4; ++r) {
            int f = r * 64 + lane;
            int srow = f >> 4, scol = f & 15;
            int nb = nbase + srow;
            if (nb < n) {
                float4 v = xg[(size_t)nb * 192 + slice * 48 + t * 16 + scol];
                *(float4*)&lx[wid][srow][scol * 4] = v;
            }
        }
#pragma unroll 4
        for (int kk = 0; kk < 16; ++kk) {
            float4 xv = *(const float4*)&lxr[kk * 4];
            int kb = (t * 16 + kk) * 4;
            fma4(xv.x, *(const float4*)&Wl[(kb + 0) * 20 + og * 4], acc);
            fma4(xv.y, *(const float4*)&Wl[(kb + 1) * 20 + og * 4], acc);
            fma4(xv.z, *(const float4*)&Wl[(kb + 2) * 20 + og * 4], acc);
            fma4(xv.w, *(const float4*)&Wl[(kb + 3) * 20 + og * 4], acc);
        }
    }
    if (node < n) {
        float4* dst = (float4*)(parts + (size_t)slice * n * 16);
        dst[(size_t)node * 4 + og] = acc;
    }
}

// ---------- reduce 4 partials, apply dinv ----------
__global__ void k_red4(const float* __restrict__ parts, const float* __restrict__ dinv,
                       float* __restrict__ u, int n) {
    int g = blockIdx.x * 256 + threadIdx.x;
    if (g >= 4 * n) return;
    size_t stride = (size_t)n * 4;
    const float4* p = (const float4*)parts;
    float4 a = p[g], b = p[g + stride], c = p[g + 2 * stride], d = p[g + 3 * stride];
    float s = dinv[g >> 2];
    float4 r;
    r.x = (a.x + b.x + c.x + d.x) * s;
    r.y = (a.y + b.y + c.y + d.y) * s;
    r.z = (a.z + b.z + c.z + d.z) * s;
    r.w = (a.w + b.w + c.w + d.w) * s;
    ((float4*)u)[g] = r;
}

// ---------- gather core: 3 hoisted masked slots (c<=48) + rare serial tail ----------
__device__ __forceinline__ float4 gather48(const float4* __restrict__ v4,
                                           const int* __restrict__ col,
                                           int beg, int c, int eslot, int comp, int n) {
    float4 a0 = {0, 0, 0, 0}, a1 = a0, a2 = a0;
    if (c > 0) {
        int i0 = eslot, i1 = eslot + 16, i2 = eslot + 32;
        int s0 = col[beg + (i0 < c ? i0 : 0)];
        int s1 = col[beg + (i1 < c ? i1 : 0)];
        int s2 = col[beg + (i2 < c ? i2 : 0)];
        s0 = (i0 < c) ? s0 : n;
        s1 = (i1 < c) ? s1 : n;
        s2 = (i2 < c) ? s2 : n;
        float4 v0 = v4[(size_t)s0 * 4 + comp];
        float4 v1 = v4[(size_t)s1 * 4 + comp];
        float4 v2 = v4[(size_t)s2 * 4 + comp];
        a0.x += v0.x; a0.y += v0.y; a0.z += v0.z; a0.w += v0.w;
        a1.x += v1.x; a1.y += v1.y; a1.z += v1.z; a1.w += v1.w;
        a2.x += v2.x; a2.y += v2.y; a2.z += v2.z; a2.w += v2.w;
        for (int i = eslot + 48; i < c; i += 16) {  // rare (P ~ 0.2%)
            int s = col[beg + i];
            float4 v = v4[(size_t)s * 4 + comp];
            a0.x += v.x; a0.y += v.y; a0.z += v.z; a0.w += v.w;
        }
    }
    a0.x += a1.x + a2.x;
    a0.y += a1.y + a2.y;
    a0.z += a1.z + a2.z;
    a0.w += a1.w + a2.w;
    for (int off = 4; off < 64; off <<= 1) {
        a0.x += __shfl_xor(a0.x, off, 64);
        a0.y += __shfl_xor(a0.y, off, 64);
        a0.z += __shfl_xor(a0.z, off, 64);
        a0.w += __shfl_xor(a0.w, off, 64);
    }
    return a0;
}

// ---------- layer-1 aggregate: v1 = dinv * relu(dinv*(sum u + self) + b) ----------
__global__ void k_agg16A(const float* __restrict__ u, const int* __restrict__ col,
                         const int* __restrict__ offs, const int* __restrict__ cnt,
                         const float* __restrict__ dinv, const float* __restrict__ b,
                         float* __restrict__ vout, int n) {
    int wave = threadIdx.x >> 6;
    int node = blockIdx.x * 4 + wave;
    if (node >= n) return;
    int lane = threadIdx.x & 63;
    int eslot = lane >> 2, comp = lane & 3;
    const float4* u4 = (const float4*)u;
    int beg = offs[node], c = cnt[node];
    float4 a0 = gather48(u4, col, beg, c, eslot, comp, n);
    if (eslot == 0) {
        float4 self = u4[(size_t)node * 4 + comp];
        float dv = dinv[node];
        float4 bb = ((const float4*)b)[comp];
        float4 r;
        r.x = dv * fmaxf(fmaf(dv, a0.x + self.x, bb.x), 0.f);
        r.y = dv * fmaxf(fmaf(dv, a0.y + self.y, bb.y), 0.f);
        r.z = dv * fmaxf(fmaf(dv, a0.z + self.z, bb.z), 0.f);
        r.w = dv * fmaxf(fmaf(dv, a0.w + self.w, bb.w), 0.f);
        ((float4*)vout)[(size_t)node * 4 + comp] = r;
    }
}

// ---------- fused aggregate+transform (layers 2,3) ----------
__global__ void k_agg16F(const float* __restrict__ vin, const int* __restrict__ col,
                         const int* __restrict__ offs, const int* __restrict__ cnt,
                         const float* __restrict__ dinv, const float* __restrict__ W,
                         const float* __restrict__ b, float* __restrict__ vout, int n) {
    __shared__ float Wl[16 * 20];
    int tid = threadIdx.x;
    if (tid < 64) {
        float4 w = ((const float4*)W)[tid];
        *(float4*)&Wl[(tid >> 2) * 20 + (tid & 3) * 4] = w;
    }
    __syncthreads();
    int wave = tid >> 6;
    int node = blockIdx.x * 4 + wave;
    if (node >= n) return;
    int lane = tid & 63;
    int eslot = lane >> 2, comp = lane & 3;
    const float4* v4 = (const float4*)vin;
    int beg = offs[node], c = cnt[node];
    float4 self = v4[(size_t)node * 4 + comp];
    float dv = dinv[node];
    float4 a0 = gather48(v4, col, beg, c, eslot, comp, n);
    float4 s;
    s.x = dv * (a0.x + self.x);
    s.y = dv * (a0.y + self.y);
    s.z = dv * (a0.z + self.z);
    s.w = dv * (a0.w + self.w);
    float4 p0 = {0, 0, 0, 0}, p1 = p0, p2 = p0, p3 = p0;
    const float* wr = &Wl[comp * 4 * 20];
#pragma unroll
    for (int i2 = 0; i2 < 4; ++i2) {
        float si = (&s.x)[i2];
        const float* row = wr + i2 * 20;
        fma4(si, *(const float4*)&row[((comp ^ 0) << 2)], p0);
        fma4(si, *(const float4*)&row[((comp ^ 1) << 2)], p1);
        fma4(si, *(const float4*)&row[((comp ^ 2) << 2)], p2);
        fma4(si, *(const float4*)&row[((comp ^ 3) << 2)], p3);
    }
    float4 o;
    o.x = p0.x + __shfl_xor(p1.x, 1, 64) + __shfl_xor(p2.x, 2, 64) + __shfl_xor(p3.x, 3, 64);
    o.y = p0.y + __shfl_xor(p1.y, 1, 64) + __shfl_xor(p2.y, 2, 64) + __shfl_xor(p3.y, 3, 64);
    o.z = p0.z + __shfl_xor(p1.z, 1, 64) + __shfl_xor(p2.z, 2, 64) + __shfl_xor(p3.z, 3, 64);
    o.w = p0.w + __shfl_xor(p1.w, 1, 64) + __shfl_xor(p2.w, 2, 64) + __shfl_xor(p3.w, 3, 64);
    if (eslot == 0) {
        float4 bb = ((const float4*)b)[comp];
        float4 r;
        r.x = dv * fmaxf(o.x + bb.x, 0.f);
        r.y = dv * fmaxf(o.y + bb.y, 0.f);
        r.z = dv * fmaxf(o.z + bb.z, 0.f);
        r.w = dv * fmaxf(o.w + bb.w, 0.f);
        ((float4*)vout)[(size_t)node * 4 + comp] = r;
    }
}

// ---------- layer-4 transform: u4 = v3 @ W4 (dinv folded into v3) ----------
__global__ void k_t4(const float* __restrict__ v3, const float* __restrict__ W4,
                     float4* __restrict__ u4p, int n) {
    int node = blockIdx.x * 256 + threadIdx.x;
    if (node >= n) return;
    const float4* hr = (const float4*)(v3 + (size_t)node * 16);
    float4 h0 = hr[0], h1 = hr[1], h2 = hr[2], h3 = hr[3];
    float hv[16] = {h0.x, h0.y, h0.z, h0.w, h1.x, h1.y, h1.z, h1.w,
                    h2.x, h2.y, h2.z, h2.w, h3.x, h3.y, h3.z, h3.w};
    float a0 = 0.f, a1 = 0.f, a2 = 0.f;
#pragma unroll
    for (int k = 0; k < 16; ++k) {
        a0 = fmaf(hv[k], W4[k * 3 + 0], a0);
        a1 = fmaf(hv[k], W4[k * 3 + 1], a1);
        a2 = fmaf(hv[k], W4[k * 3 + 2], a2);
    }
    u4p[node] = make_float4(a0, a1, a2, 0.f);
}

// ---------- final aggregate + log_softmax ----------
__global__ void k_agg_out(const float4* __restrict__ u4p, const int* __restrict__ col,
                          const int* __restrict__ offs, const int* __restrict__ cnt,
                          const float* __restrict__ dinv, const float* __restrict__ b4,
                          float* __restrict__ out, int n) {
    int wave = threadIdx.x >> 6;
    int node = blockIdx.x * 4 + wave;
    if (node >= n) return;
    int lane = threadIdx.x & 63;
    int beg = offs[node], c = cnt[node];
    float a0 = 0.f, a1 = 0.f, a2 = 0.f;
    if (c > 0) {
        int s0 = col[beg + (lane < c ? lane : 0)];
        s0 = (lane < c) ? s0 : n;
        float4 v = u4p[s0];
        a0 += v.x; a1 += v.y; a2 += v.z;
        for (int i = lane + 64; i < c; i += 64) {  // rare
            float4 w = u4p[col[beg + i]];
            a0 += w.x; a1 += w.y; a2 += w.z;
        }
    }
    for (int off = 1; off < 64; off <<= 1) {
        a0 += __shfl_xor(a0, off, 64);
        a1 += __shfl_xor(a1, off, 64);
        a2 += __shfl_xor(a2, off, 64);
    }
    if (lane == 0) {
        float4 self = u4p[node];
        float dv = dinv[node];
        float v0 = fmaf(dv, a0 + self.x, b4[0]);
        float v1 = fmaf(dv, a1 + self.y, b4[1]);
        float v2 = fmaf(dv, a2 + self.z, b4[2]);
        float m = fmaxf(v0, fmaxf(v1, v2));
        float lse = m + logf(expf(v0 - m) + expf(v1 - m) + expf(v2 - m));
        out[(size_t)node * 3 + 0] = v0 - lse;
        out[(size_t)node * 3 + 1] = v1 - lse;
        out[(size_t)node * 3 + 2] = v2 - lse;
    }
}

extern "C" void kernel_launch(void* const* d_in, const int* in_sizes, int n_in,
                              void* d_out, int out_size, void* d_ws, size_t ws_size,
                              hipStream_t stream) {
    const float* x  = (const float*)d_in[0];
    const void*  ei = d_in[1];
    const float* W1 = (const float*)d_in[2];
    const float* b1 = (const float*)d_in[3];
    const float* W2 = (const float*)d_in[4];
    const float* b2 = (const float*)d_in[5];
    const float* W3 = (const float*)d_in[6];
    const float* b3 = (const float*)d_in[7];
    const float* W4 = (const float*)d_in[8];
    const float* b4 = (const float*)d_in[9];
    float* out = (float*)d_out;

    const int N = in_sizes[0] / 768;
    const int E = in_sizes[1] / 2;

    char* p = (char*)d_ws;
    auto alloc = [&](size_t bytes) {
        void* r = (void*)p;
        p += (bytes + 255) & ~(size_t)255;
        return r;
    };
    int*   cnt   = (int*)alloc((size_t)N * 4);
    int*   offs  = (int*)alloc((size_t)N * 4);
    int*   flag  = (int*)alloc(256);
    int*   gcur  = (int*)alloc(1024);
    int*   bbase = (int*)alloc(1024);
    float* dinv  = (float*)alloc((size_t)N * 4);
    int*   col   = (int*)alloc((size_t)E * 4);
    float* bufU  = (float*)alloc((size_t)(N + 1) * 16 * 4);  // +pad row n
    float* bufA  = (float*)alloc((size_t)(N + 1) * 16 * 4);  // +pad row n
    float4* u4p  = (float4*)alloc((size_t)(N + 1) * 16);     // +pad row n
    void* big    = alloc((size_t)NBUCK * BCAP * 8);          // ebuf/parts union
    int2*  ebuf  = (int2*)big;
    float* parts = (float*)big;

    const int nbN = DIVUP(N, 256);
    const int nbB = DIVUP(E, 2048);
    const int nbT = DIVUP(4 * N, 256);
    const int nbA = DIVUP(N, 4);
    const int nbX = DIVUP(N, 64) * 4;

    // CSR build
    k_detect<<<1, 64, 0, stream>>>(ei, flag);
    k_zero<<<1, 256, 0, stream>>>(gcur, bufU, bufA, u4p, N);
    k_bucket<<<nbB, 256, 0, stream>>>(ei, flag, gcur, ebuf, E);
    k_bscan<<<1, 128, 0, stream>>>(gcur, bbase);
    k_build<<<NBUCK, 512, 0, stream>>>(ebuf, gcur, bbase, offs, cnt, dinv, col, N);

    // layer 1 (t768 after build: parts aliases ebuf)
    k_transform768<<<nbX, 256, 0, stream>>>(x, W1, parts, N);
    k_red4<<<nbT, 256, 0, stream>>>(parts, dinv, bufU, N);
    k_agg16A<<<nbA, 256, 0, stream>>>(bufU, col, offs, cnt, dinv, b1, bufA, N);
    // layers 2,3 fused aggregate+transform
    k_agg16F<<<nbA, 256, 0, stream>>>(bufA, col, offs, cnt, dinv, W2, b2, bufU, N);
    k_agg16F<<<nbA, 256, 0, stream>>>(bufU, col, offs, cnt, dinv, W3, b3, bufA, N);
    // layer 4
    k_t4<<<nbN, 256, 0, stream>>>(bufA, W4, u4p, N);
    k_agg_out<<<nbA, 256, 0, stream>>>(u4p, col, offs, cnt, dinv, b4, out, N);
}